// Round 3
// baseline (5558.301 us; speedup 1.0000x reference)
//
#include <hip/hip_runtime.h>
#include <stdint.h>

#define N_SITES 144
#define NHID    256
#define NSAMP   1024
#define MB      4          // samples per block
#define TPB     768        // one gate-column per thread; 12 waves = 3 waves/SIMD
#define PREC    96         // rows of rec held persistently in VGPRs (col-slice per thread)
#define PARTITIONABLE 1

__device__ __forceinline__ uint32_t rotl32(uint32_t v, uint32_t r) {
    return (v << r) | (v >> (32u - r));
}

// JAX threefry2x32: 20 rounds, key injections every 4
__device__ __forceinline__ void threefry(uint32_t k0, uint32_t k1,
                                         uint32_t x0, uint32_t x1,
                                         uint32_t& o0, uint32_t& o1) {
    uint32_t ks0 = k0, ks1 = k1, ks2 = k0 ^ k1 ^ 0x1BD11BDAu;
    x0 += ks0; x1 += ks1;
#define RG4(a,b,c,d) \
    x0 += x1; x1 = rotl32(x1,a); x1 ^= x0; \
    x0 += x1; x1 = rotl32(x1,b); x1 ^= x0; \
    x0 += x1; x1 = rotl32(x1,c); x1 ^= x0; \
    x0 += x1; x1 = rotl32(x1,d); x1 ^= x0;
    RG4(13,15,26,6)  x0 += ks1; x1 += ks2 + 1u;
    RG4(17,29,16,24) x0 += ks2; x1 += ks0 + 2u;
    RG4(13,15,26,6)  x0 += ks0; x1 += ks1 + 3u;
    RG4(17,29,16,24) x0 += ks1; x1 += ks2 + 4u;
    RG4(13,15,26,6)  x0 += ks2; x1 += ks0 + 5u;
#undef RG4
    o0 = x0; o1 = x1;
}

__device__ __forceinline__ float gumbel_from_bits(uint32_t bits) {
#pragma clang fp contract(off)
    const float TINY = 1.17549435e-38f;          // finfo(f32).tiny
    uint32_t fb = (bits >> 9) | 0x3f800000u;
    float u = __uint_as_float(fb) - 1.0f;        // [0,1)
    u = u * (1.0f - TINY) + TINY;                // matches JAX uniform()
    u = fmaxf(TINY, u);
    return -logf(-logf(u));
}

__global__ __launch_bounds__(TPB, 3)   // 3 waves/EU floor -> VGPR cap ~170, no spill room issues
void rnn_sample_kernel(const float* __restrict__ kern,   // [2,768]
                       const float* __restrict__ rec,    // [256,768]
                       const float* __restrict__ bias,   // [2,768]
                       const float* __restrict__ dw,     // [256,2]
                       const float* __restrict__ db,     // [2]
                       float* __restrict__ out)          // samples[1024*144] ++ logP[1024]
{
    const int t    = threadIdx.x;          // 0..767 == gate column index
    const int blk  = blockIdx.x;
    const int b0   = blk * MB;
    const int wv   = t >> 6;               // wave id (phase C uses 0..3)
    const int lane = t & 63;

    __shared__ float4   hs4[NHID];          // h[k] packed over 4 samples (4 KB)
    __shared__ float    pacc[MB][TPB];      // phase-A partials, [sample][col] (12 KB)
    __shared__ uint32_t keyA[N_SITES], keyB[N_SITES];
    __shared__ float    glds[N_SITES][MB][2];  // precomputed gumbels (4.6 KB)
    __shared__ float    wred[4][8];         // per-wave dense partials (waves 0..3)
    __shared__ int      sPrev[MB];
    __shared__ float    lgP[MB];

    // ---- persistent weight slice: rows 0..PREC-1 of this thread's column ----
    // rec is constant across all 144 steps; re-loading it from L2 every step was
    // 786 KB/CU/step. Holding 96 rows in VGPRs cuts streamed traffic 37% and
    // removes 96 load+addr ops from the per-step critical chain.
    float wreg[PREC];
#pragma unroll
    for (int r = 0; r < PREC; ++r) wreg[r] = rec[(size_t)r * 768 + t];

    // ---- per-thread constants (threads 0..255 only: gate triples) ----
    float kz0 = 0.f, kr0 = 0.f, kn0 = 0.f, kz1 = 0.f, kr1 = 0.f, kn1 = 0.f;
    float b0z = 0.f, b0r = 0.f, b0n = 0.f, b1z = 0.f, b1r = 0.f, b1n = 0.f;
    float dwa = 0.f, dwb = 0.f, dba = 0.f, dbb = 0.f;
    float hreg[MB] = { 0.f, 0.f, 0.f, 0.f };          // own h row, registers
    if (t < NHID) {
        const int c0 = t, c1 = t + 256, c2 = t + 512;
        kz0 = kern[c0];       kr0 = kern[c1];       kn0 = kern[c2];
        b0z = bias[c0];       b0r = bias[c1];       b0n = bias[c2];
        kz1 = kern[768 + c0]; kr1 = kern[768 + c1]; kn1 = kern[768 + c2];
        b1z = bias[768 + c0]; b1r = bias[768 + c1]; b1n = bias[768 + c2];
        dwa = dw[2 * t];      dwb = dw[2 * t + 1];
        dba = db[0];          dbb = db[1];
        hs4[t] = make_float4(0.f, 0.f, 0.f, 0.f);
    }
    if (t < MB) { sPrev[t] = -1; lgP[t] = 0.f; }
    if (t < N_SITES) {
        uint32_t o0, o1;
        threefry(0u, 42u, 0u, (uint32_t)t, o0, o1);   // foldlike split: counter = n
        keyA[t] = o0; keyB[t] = o1;
    }
    __syncthreads();

    // ---- gumbel precompute: data-independent, hoisted out of the step loop ----
    if (t < N_SITES * MB) {
        const int n = t >> 2, m = t & 3;
        uint32_t o0a, o1a, o0b, o1b;
        const uint32_t fbase = 2u * (uint32_t)(b0 + m);
        threefry(keyA[n], keyB[n], 0u, fbase,      o0a, o1a);
        threefry(keyA[n], keyB[n], 0u, fbase + 1u, o0b, o1b);
        glds[n][m][0] = gumbel_from_bits(o0a ^ o1a);
        glds[n][m][1] = gumbel_from_bits(o0b ^ o1b);
    }
    __syncthreads();

    for (int n = 0; n < N_SITES; ++n) {
        // ---- phase A: one column per thread, single-accumulator k=0..255 chain
        //      (bit-identical order; rows 0..95 from VGPR, 96..255 streamed) ----
        float a0 = 0.f, a1 = 0.f, a2 = 0.f, a3 = 0.f;
        {
#pragma unroll
            for (int k = 0; k < PREC; ++k) {
                float4 h4 = hs4[k];          // broadcast ds_read_b128
                a0 = fmaf(h4.x, wreg[k], a0);
                a1 = fmaf(h4.y, wreg[k], a1);
                a2 = fmaf(h4.z, wreg[k], a2);
                a3 = fmaf(h4.w, wreg[k], a3);
            }
            const float* rp = rec + (size_t)PREC * 768 + t;
#pragma unroll 16
            for (int k = PREC; k < NHID; ++k) {
                float4 h4 = hs4[k];
                float w  = rp[0];
                rp += 768;
                a0 = fmaf(h4.x, w, a0);
                a1 = fmaf(h4.y, w, a1);
                a2 = fmaf(h4.z, w, a2);
                a3 = fmaf(h4.w, w, a3);
            }
        }
        pacc[0][t] = a0; pacc[1][t] = a1; pacc[2][t] = a2; pacc[3][t] = a3;
        __syncthreads();   // B1: pacc ready; all hs4 reads complete

        // ---- phases B+C: threads 0..255 (gates, h update, dense partials) ----
        float hnew[MB];
        if (t < NHID) {
            {
#pragma clang fp contract(off)
#pragma unroll
                for (int m = 0; m < MB; ++m) {
                    const int sp = sPrev[m];
                    float xz = (sp == 0) ? kz0 : ((sp == 1) ? kz1 : 0.f);
                    float xr = (sp == 0) ? kr0 : ((sp == 1) ? kr1 : 0.f);
                    float xh = (sp == 0) ? kn0 : ((sp == 1) ? kn1 : 0.f);
                    xz = xz + b0z;  xr = xr + b0r;  xh = xh + b0n;
                    const float hz = pacc[m][t]       + b1z;
                    const float hr = pacc[m][t + 256] + b1r;
                    const float hn = pacc[m][t + 512] + b1n;
                    const float z = 1.0f / (1.0f + expf(-(xz + hz)));
                    const float r = 1.0f / (1.0f + expf(-(xr + hr)));
                    const float rhn = r * hn;
                    const float hh = tanhf(xh + rhn);
                    hnew[m] = z * hreg[m] + (1.0f - z) * hh;
                    hreg[m] = hnew[m];
                }
            }
            hs4[t] = make_float4(hnew[0], hnew[1], hnew[2], hnew[3]);

            // dense logits partial reduction (h @ dense_w), waves 0..3
#pragma unroll
            for (int m = 0; m < MB; ++m) {
                float va = hnew[m] * dwa;
                float vb = hnew[m] * dwb;
#pragma unroll
                for (int off = 32; off > 0; off >>= 1) {
                    va += __shfl_xor(va, off, 64);
                    vb += __shfl_xor(vb, off, 64);
                }
                if (lane == 0) { wred[wv][2 * m] = va; wred[wv][2 * m + 1] = vb; }
            }
        }
        __syncthreads();   // B2: wred + hs4 ready

        // ---- phase D: logits + categorical + logP (4 threads, gumbels precomputed) ----
        if (t < MB) {
            const int m = t;
            // same summation order as the verified kernel: w0+w1+w2+w3, then bias
            float l0 = wred[0][2 * m] + wred[1][2 * m] + wred[2][2 * m] + wred[3][2 * m];
            float l1 = wred[0][2 * m + 1] + wred[1][2 * m + 1] + wred[2][2 * m + 1] + wred[3][2 * m + 1];
            const float g0 = glds[n][m][0];
            const float g1 = glds[n][m][1];
            {
#pragma clang fp contract(off)
                l0 = l0 + dba;
                l1 = l1 + dbb;
                const float mx = fmaxf(l0, l1);
                const float e0 = expf(l0 - mx), e1 = expf(l1 - mx);
                const float den = e0 + e1;
                const float lp0 = logf(1e-10f + e0 / den);
                const float lp1 = logf(1e-10f + e1 / den);
                const float v0 = g0 + lp0;
                const float v1 = g1 + lp1;
                const int s = (v1 > v0) ? 1 : 0;   // argmax, first-index tie-break
                sPrev[m] = s;
                lgP[m] = lgP[m] + (s ? lp1 : lp0);
                out[(size_t)(b0 + m) * N_SITES + n] = (float)s;
            }
        }
        // NOTE: no third barrier. Phase D writes (sPrev/lgP/out) are ordered
        // against next-step readers by B1(n+1); pacc/hs4 races are excluded by
        // the same read-before-barrier/write-after-barrier structure.
    }

    __syncthreads();
    if (t < MB) out[(size_t)NSAMP * N_SITES + (b0 + t)] = lgP[t];
}

extern "C" void kernel_launch(void* const* d_in, const int* in_sizes, int n_in,
                              void* d_out, int out_size, void* d_ws, size_t ws_size,
                              hipStream_t stream) {
    (void)in_sizes; (void)n_in; (void)d_ws; (void)ws_size; (void)out_size;
    const float* kern = (const float*)d_in[0];
    const float* rec  = (const float*)d_in[1];
    const float* bias = (const float*)d_in[2];
    const float* dwp  = (const float*)d_in[3];
    const float* dbp  = (const float*)d_in[4];
    float* out = (float*)d_out;
    rnn_sample_kernel<<<NSAMP / MB, TPB, 0, stream>>>(kern, rec, bias, dwp, dbp, out);
}

// Round 4
// 2364.373 us; speedup vs baseline: 2.3509x; 2.3509x over previous
//
#include <hip/hip_runtime.h>
#include <stdint.h>

#define N_SITES 144
#define NHID    256
#define NSAMP   1024
#define MB      4          // samples per block
#define TPB     768        // one gate-column per thread; 12 waves = 3 waves/SIMD
#define R_LDS   40         // rec rows 0..39 resident in LDS (120 KB, bypasses L1)
#define R_REG   32         // rec rows 40..71 resident in VGPRs (32 regs, no spill)
#define R_CACHED (R_LDS + R_REG)
#define PARTITIONABLE 1

__device__ __forceinline__ uint32_t rotl32(uint32_t v, uint32_t r) {
    return (v << r) | (v >> (32u - r));
}

// JAX threefry2x32: 20 rounds, key injections every 4
__device__ __forceinline__ void threefry(uint32_t k0, uint32_t k1,
                                         uint32_t x0, uint32_t x1,
                                         uint32_t& o0, uint32_t& o1) {
    uint32_t ks0 = k0, ks1 = k1, ks2 = k0 ^ k1 ^ 0x1BD11BDAu;
    x0 += ks0; x1 += ks1;
#define RG4(a,b,c,d) \
    x0 += x1; x1 = rotl32(x1,a); x1 ^= x0; \
    x0 += x1; x1 = rotl32(x1,b); x1 ^= x0; \
    x0 += x1; x1 = rotl32(x1,c); x1 ^= x0; \
    x0 += x1; x1 = rotl32(x1,d); x1 ^= x0;
    RG4(13,15,26,6)  x0 += ks1; x1 += ks2 + 1u;
    RG4(17,29,16,24) x0 += ks2; x1 += ks0 + 2u;
    RG4(13,15,26,6)  x0 += ks0; x1 += ks1 + 3u;
    RG4(17,29,16,24) x0 += ks1; x1 += ks2 + 4u;
    RG4(13,15,26,6)  x0 += ks2; x1 += ks0 + 5u;
#undef RG4
    o0 = x0; o1 = x1;
}

__device__ __forceinline__ float gumbel_from_bits(uint32_t bits) {
#pragma clang fp contract(off)
    const float TINY = 1.17549435e-38f;          // finfo(f32).tiny
    uint32_t fb = (bits >> 9) | 0x3f800000u;
    float u = __uint_as_float(fb) - 1.0f;        // [0,1)
    u = u * (1.0f - TINY) + TINY;                // matches JAX uniform()
    u = fmaxf(TINY, u);
    return -logf(-logf(u));
}

__global__ __launch_bounds__(TPB, 1)   // (TPB,1) as in rounds 0-2: sane VGPR allocation
void rnn_sample_kernel(const float* __restrict__ kern,   // [2,768]
                       const float* __restrict__ rec,    // [256,768]
                       const float* __restrict__ bias,   // [2,768]
                       const float* __restrict__ dw,     // [256,2]
                       const float* __restrict__ db,     // [2]
                       float* __restrict__ out)          // samples[1024*144] ++ logP[1024]
{
    const int t    = threadIdx.x;          // 0..767 == gate column index
    const int blk  = blockIdx.x;
    const int b0   = blk * MB;
    const int wv   = t >> 6;               // wave id (phase C uses 0..3)
    const int lane = t & 63;

    __shared__ float    wlds[R_LDS][TPB];   // 120 KB: weight rows 0..39, L1-bypass
    __shared__ float4   hs4[NHID];          // h[k] packed over 4 samples (4 KB)
    __shared__ float    pacc[MB][TPB];      // phase-A partials, [sample][col] (12 KB)
    __shared__ uint32_t keyA[N_SITES], keyB[N_SITES];
    __shared__ float    glds[N_SITES][MB][2];  // precomputed gumbels (4.6 KB)
    __shared__ float    wred[4][8];         // per-wave dense partials (waves 0..3)
    __shared__ int      sPrev[MB];
    __shared__ float    lgP[MB];

    // ---- weight residency: rows 0..39 -> LDS (coalesced stage, done once) ----
    // Each CU was re-streaming all 786 KB of rec from L2 through L1 every step
    // (~5.1 us/step at ~64 B/cyc L1 fill -- the measured limiter; rounds 0/2
    // proved h-delivery path is NOT the limiter). Rows cached in LDS/VGPR are
    // removed from that stream. k-chain order 0..255 is unchanged -> bit-exact.
#pragma unroll
    for (int r = 0; r < R_LDS; ++r) wlds[r][t] = rec[(size_t)r * TPB + t];

    // ---- rows 40..71 -> VGPRs (32 regs; small enough to never spill) ----
    float wreg[R_REG];
#pragma unroll
    for (int j = 0; j < R_REG; ++j) wreg[j] = rec[(size_t)(R_LDS + j) * TPB + t];

    // ---- per-thread constants (threads 0..255 only: gate triples) ----
    float kz0 = 0.f, kr0 = 0.f, kn0 = 0.f, kz1 = 0.f, kr1 = 0.f, kn1 = 0.f;
    float b0z = 0.f, b0r = 0.f, b0n = 0.f, b1z = 0.f, b1r = 0.f, b1n = 0.f;
    float dwa = 0.f, dwb = 0.f, dba = 0.f, dbb = 0.f;
    float hreg[MB] = { 0.f, 0.f, 0.f, 0.f };          // own h row, registers
    if (t < NHID) {
        const int c0 = t, c1 = t + 256, c2 = t + 512;
        kz0 = kern[c0];       kr0 = kern[c1];       kn0 = kern[c2];
        kz1 = kern[768 + c0]; kr1 = kern[768 + c1]; kn1 = kern[768 + c2];
        b0z = bias[c0];       b0r = bias[c1];       b0n = bias[c2];
        b1z = bias[768 + c0]; b1r = bias[768 + c1]; b1n = bias[768 + c2];
        dwa = dw[2 * t];      dwb = dw[2 * t + 1];
        dba = db[0];          dbb = db[1];
        hs4[t] = make_float4(0.f, 0.f, 0.f, 0.f);
    }
    if (t < MB) { sPrev[t] = -1; lgP[t] = 0.f; }
    if (t < N_SITES) {
        uint32_t o0, o1;
        threefry(0u, 42u, 0u, (uint32_t)t, o0, o1);   // foldlike split: counter = n
        keyA[t] = o0; keyB[t] = o1;
    }
    __syncthreads();

    // ---- gumbel precompute: data-independent, hoisted out of the step loop ----
    if (t < N_SITES * MB) {
        const int n = t >> 2, m = t & 3;
        uint32_t o0a, o1a, o0b, o1b;
        const uint32_t fbase = 2u * (uint32_t)(b0 + m);
        threefry(keyA[n], keyB[n], 0u, fbase,      o0a, o1a);
        threefry(keyA[n], keyB[n], 0u, fbase + 1u, o0b, o1b);
        glds[n][m][0] = gumbel_from_bits(o0a ^ o1a);
        glds[n][m][1] = gumbel_from_bits(o0b ^ o1b);
    }
    __syncthreads();

    for (int n = 0; n < N_SITES; ++n) {
        // ---- phase A: one column per thread, single-accumulator k=0..255 chain
        //      (bit-identical order; k<40 LDS, 40..71 VGPR, 72..255 streamed) ----
        float a0 = 0.f, a1 = 0.f, a2 = 0.f, a3 = 0.f;
        {
#pragma unroll 8
            for (int k = 0; k < R_LDS; ++k) {
                float4 h4 = hs4[k];          // broadcast ds_read_b128
                float w  = wlds[k][t];       // conflict-free lane-consecutive read
                a0 = fmaf(h4.x, w, a0);
                a1 = fmaf(h4.y, w, a1);
                a2 = fmaf(h4.z, w, a2);
                a3 = fmaf(h4.w, w, a3);
            }
#pragma unroll
            for (int j = 0; j < R_REG; ++j) {
                float4 h4 = hs4[R_LDS + j];
                a0 = fmaf(h4.x, wreg[j], a0);
                a1 = fmaf(h4.y, wreg[j], a1);
                a2 = fmaf(h4.z, wreg[j], a2);
                a3 = fmaf(h4.w, wreg[j], a3);
            }
            const float* rp = rec + (size_t)R_CACHED * TPB + t;
#pragma unroll 8
            for (int k = R_CACHED; k < NHID; ++k) {
                float4 h4 = hs4[k];
                float w  = rp[0];
                rp += TPB;
                a0 = fmaf(h4.x, w, a0);
                a1 = fmaf(h4.y, w, a1);
                a2 = fmaf(h4.z, w, a2);
                a3 = fmaf(h4.w, w, a3);
            }
        }
        pacc[0][t] = a0; pacc[1][t] = a1; pacc[2][t] = a2; pacc[3][t] = a3;
        __syncthreads();   // B1: pacc ready; all hs4 reads complete

        // ---- phases B+C: threads 0..255 (gates, h update, dense partials) ----
        float hnew[MB];
        if (t < NHID) {
            {
#pragma clang fp contract(off)
#pragma unroll
                for (int m = 0; m < MB; ++m) {
                    const int sp = sPrev[m];
                    float xz = (sp == 0) ? kz0 : ((sp == 1) ? kz1 : 0.f);
                    float xr = (sp == 0) ? kr0 : ((sp == 1) ? kr1 : 0.f);
                    float xh = (sp == 0) ? kn0 : ((sp == 1) ? kn1 : 0.f);
                    xz = xz + b0z;  xr = xr + b0r;  xh = xh + b0n;
                    const float hz = pacc[m][t]       + b1z;
                    const float hr = pacc[m][t + 256] + b1r;
                    const float hn = pacc[m][t + 512] + b1n;
                    const float z = 1.0f / (1.0f + expf(-(xz + hz)));
                    const float r = 1.0f / (1.0f + expf(-(xr + hr)));
                    const float rhn = r * hn;
                    const float hh = tanhf(xh + rhn);
                    hnew[m] = z * hreg[m] + (1.0f - z) * hh;
                    hreg[m] = hnew[m];
                }
            }
            hs4[t] = make_float4(hnew[0], hnew[1], hnew[2], hnew[3]);

            // dense logits partial reduction (h @ dense_w), waves 0..3
#pragma unroll
            for (int m = 0; m < MB; ++m) {
                float va = hnew[m] * dwa;
                float vb = hnew[m] * dwb;
#pragma unroll
                for (int off = 32; off > 0; off >>= 1) {
                    va += __shfl_xor(va, off, 64);
                    vb += __shfl_xor(vb, off, 64);
                }
                if (lane == 0) { wred[wv][2 * m] = va; wred[wv][2 * m + 1] = vb; }
            }
        }
        __syncthreads();   // B2: wred + hs4 ready

        // ---- phase D: logits + categorical + logP (4 threads, gumbels precomputed) ----
        if (t < MB) {
            const int m = t;
            // same summation order as the verified kernel: w0+w1+w2+w3, then bias
            float l0 = wred[0][2 * m] + wred[1][2 * m] + wred[2][2 * m] + wred[3][2 * m];
            float l1 = wred[0][2 * m + 1] + wred[1][2 * m + 1] + wred[2][2 * m + 1] + wred[3][2 * m + 1];
            const float g0 = glds[n][m][0];
            const float g1 = glds[n][m][1];
            {
#pragma clang fp contract(off)
                l0 = l0 + dba;
                l1 = l1 + dbb;
                const float mx = fmaxf(l0, l1);
                const float e0 = expf(l0 - mx), e1 = expf(l1 - mx);
                const float den = e0 + e1;
                const float lp0 = logf(1e-10f + e0 / den);
                const float lp1 = logf(1e-10f + e1 / den);
                const float v0 = g0 + lp0;
                const float v1 = g1 + lp1;
                const int s = (v1 > v0) ? 1 : 0;   // argmax, first-index tie-break
                sPrev[m] = s;
                lgP[m] = lgP[m] + (s ? lp1 : lp0);
                out[(size_t)(b0 + m) * N_SITES + n] = (float)s;
            }
        }
        // No third barrier: phase D writes only sPrev/lgP/out; every next-step
        // reader of those is behind B1(n+1). pacc/hs4 writes are all pre-B2.
    }

    __syncthreads();
    if (t < MB) out[(size_t)NSAMP * N_SITES + (b0 + t)] = lgP[t];
}

extern "C" void kernel_launch(void* const* d_in, const int* in_sizes, int n_in,
                              void* d_out, int out_size, void* d_ws, size_t ws_size,
                              hipStream_t stream) {
    (void)in_sizes; (void)n_in; (void)d_ws; (void)ws_size; (void)out_size;
    const float* kern = (const float*)d_in[0];
    const float* rec  = (const float*)d_in[1];
    const float* bias = (const float*)d_in[2];
    const float* dwp  = (const float*)d_in[3];
    const float* dbp  = (const float*)d_in[4];
    float* out = (float*)d_out;
    rnn_sample_kernel<<<NSAMP / MB, TPB, 0, stream>>>(kern, rec, bias, dwp, dbp, out);
}